// Round 5
// baseline (47128.827 us; speedup 1.0000x reference)
//
#include <hip/hip_runtime.h>
#include <cstddef>

#define T_LEN 131072

typedef float float4_t __attribute__((ext_vector_type(4)));

__device__ __forceinline__ float fast_sigmoid(float x) {
  float e = __builtin_amdgcn_exp2f(x * -1.44269504088896340736f);
  return __builtin_amdgcn_rcpf(1.0f + e);
}

__device__ __forceinline__ float fast_tanh(float x) {
  float e = __builtin_amdgcn_exp2f(x * 2.88539008177792681472f);
  return 1.0f - 2.0f * __builtin_amdgcn_rcpf(1.0f + e);
}

// ---------------------------------------------------------------------------
// Kernel A (parallel over T): hs_in = relu(x@W1+b1); gates[t] = hs_in @ {Wir,Wiz,Win} + b
// gates layout: [T][3][64] fp32
// ---------------------------------------------------------------------------
__global__ __launch_bounds__(256) void prep_kernel(
    const float* __restrict__ obs, const float* __restrict__ W1,
    const float* __restrict__ b1,
    const float* __restrict__ Wir, const float* __restrict__ bir,
    const float* __restrict__ Wiz, const float* __restrict__ biz,
    const float* __restrict__ Win, const float* __restrict__ bin,
    float* __restrict__ gates)
{
  __shared__ float sW1[36 * 64];
  __shared__ float sWg[3 * 4096];
  __shared__ float sb1[64];
  __shared__ float sbg[3 * 64];
  for (int i = threadIdx.x; i < 36 * 64; i += 256) sW1[i] = W1[i];
  for (int i = threadIdx.x; i < 4096; i += 256) {
    sWg[i] = Wir[i];
    sWg[4096 + i] = Wiz[i];
    sWg[8192 + i] = Win[i];
  }
  if (threadIdx.x < 64) {
    sb1[threadIdx.x] = b1[threadIdx.x];
    sbg[threadIdx.x] = bir[threadIdx.x];
    sbg[64 + threadIdx.x] = biz[threadIdx.x];
    sbg[128 + threadIdx.x] = bin[threadIdx.x];
  }
  __syncthreads();

  const int t = blockIdx.x * 256 + threadIdx.x;   // T divisible by 256

  float4_t x4[9];
  {
    const float4_t* op = (const float4_t*)(obs + (size_t)t * 36);
#pragma unroll
    for (int c = 0; c < 9; c++) x4[c] = op[c];
  }
  float4_t hacc[16];
  {
    const float4_t* bv = (const float4_t*)sb1;
#pragma unroll
    for (int k = 0; k < 16; k++) hacc[k] = bv[k];
  }
#pragma unroll
  for (int c = 0; c < 9; c++) {
#pragma unroll
    for (int q = 0; q < 4; q++) {
      const float xv = x4[c][q];
      const float4_t* wrow = (const float4_t*)(sW1 + (c * 4 + q) * 64);
#pragma unroll
      for (int k = 0; k < 16; k++) hacc[k] += xv * wrow[k];
    }
  }
#pragma unroll
  for (int k = 0; k < 16; k++) {
    hacc[k].x = fmaxf(hacc[k].x, 0.0f);
    hacc[k].y = fmaxf(hacc[k].y, 0.0f);
    hacc[k].z = fmaxf(hacc[k].z, 0.0f);
    hacc[k].w = fmaxf(hacc[k].w, 0.0f);
  }

  float* gout = gates + (size_t)t * 192;
  for (int g = 0; g < 3; g++) {   // rolled: caps register pressure
    const float* wg = sWg + g * 4096;
    float4_t acc[16];
    {
      const float4_t* bv = (const float4_t*)(sbg + g * 64);
#pragma unroll
      for (int k = 0; k < 16; k++) acc[k] = bv[k];
    }
#pragma unroll
    for (int ii = 0; ii < 16; ii++) {
      const float4_t hv4 = hacc[ii];
#pragma unroll
      for (int q = 0; q < 4; q++) {
        const float hv = hv4[q];
        const float4_t* wrow = (const float4_t*)(wg + (ii * 4 + q) * 64);
#pragma unroll
        for (int k = 0; k < 16; k++) acc[k] += hv * wrow[k];
      }
    }
    float4_t* outp = (float4_t*)(gout + g * 64);
#pragma unroll
    for (int k = 0; k < 16; k++) outp[k] = acc[k];
  }
}

// ---------------------------------------------------------------------------
// Kernel B (sequential): 4 waves, K-split GRU scan. FP32.
// R4 post-mortem: single-wave is VALU-floor-bound at 384 cyc/step (192 fp32
// FMA/lane x 2cyc) and the allocator keeps weights in LDS anyway. Here the
// matvec K-dim splits across 4 waves (4 SIMDs): 48 FMA/lane/step, weights
// only 48 VGPRs/lane (no pressure). Cross-wave reduce via double-buffered
// LDS partials + a hand-rolled barrier that drains ONLY lgkmcnt — in-flight
// global gate prefetches survive (s_barrier via __syncthreads would drain
// vmcnt(0) and serialize on L2 latency every step). Tail computed per-wave
// for its own 16 outputs (lanes 16-63 redundant, same-address LDS reads =
// broadcast); next-step h distributed by 16 v_readlane into SGPRs — wave w's
// tail outputs are exactly its own k-chunk, so no second barrier.
// ---------------------------------------------------------------------------
#define REP16(X) X(0) X(1) X(2) X(3) X(4) X(5) X(6) X(7) \
                 X(8) X(9) X(10) X(11) X(12) X(13) X(14) X(15)
#define REP4(X) X(0) X(1) X(2) X(3)

#define DECLW(c) float wr##c, wz##c, wn##c;
#define INITW(c) \
  wr##c = sW[(kbase + (c)) * 64 + j]; \
  wz##c = sW[4096 + (kbase + (c)) * 64 + j]; \
  wn##c = sW[8192 + (kbase + (c)) * 64 + j];
// VOLATILE pin (R4's non-volatile asm was sinkable — that was the bug):
#define PINW(c) asm volatile("" : "+v"(wr##c), "+v"(wz##c), "+v"(wn##c));

#define DECLH(c) float hh##c = 0.0f;
#define RL(c) hh##c = __builtin_bit_cast(float, \
    __builtin_amdgcn_readlane(__builtin_bit_cast(int, hn), (c)));

// two k-elements of all three gate partials: 6 scalar v_fma_f32 (SGPR h src)
#define FMA2(ce, co) \
  sR0 = __builtin_fmaf(wr##ce, hh##ce, sR0); sR1 = __builtin_fmaf(wr##co, hh##co, sR1); \
  sZ0 = __builtin_fmaf(wz##ce, hh##ce, sZ0); sZ1 = __builtin_fmaf(wz##co, hh##co, sZ1); \
  sN0 = __builtin_fmaf(wn##ce, hh##ce, sN0); sN1 = __builtin_fmaf(wn##co, hh##co, sN1);

#define DECLP(d) float pr##d, pz##d, pn##d;
#define PROLOAD(d) \
  pr##d = g0[(d) * 192]; \
  pz##d = g0[(d) * 192 + 64]; \
  pn##d = g0[(d) * 192 + 128];

// LDS-only barrier: drains ds ops, leaves global loads in flight.
#define LDS_BARRIER() asm volatile("s_waitcnt lgkmcnt(0)\n\ts_barrier" ::: "memory")

#define STEP(d) { \
  const float xr = pr##d, xz = pz##d, xn = pn##d; \
  pr##d = gpf[0]; pz##d = gpf[64]; pn##d = gpf[128]; gpf += 192; \
  float sR0 = 0.f, sR1 = 0.f, sZ0 = 0.f, sZ1 = 0.f, sN0 = 0.f, sN1 = 0.f; \
  FMA2(0,1) FMA2(2,3) FMA2(4,5) FMA2(6,7) \
  FMA2(8,9) FMA2(10,11) FMA2(12,13) FMA2(14,15) \
  partf4[((d)&1)*256 + wslot + j] = float4_t{sR0 + sR1, sZ0 + sZ1, sN0 + sN1, 0.0f}; \
  LDS_BARRIER(); \
  const float4_t q0 = partf4[((d)&1)*256 +       jr]; \
  const float4_t q1 = partf4[((d)&1)*256 +  64 + jr]; \
  const float4_t q2 = partf4[((d)&1)*256 + 128 + jr]; \
  const float4_t q3 = partf4[((d)&1)*256 + 192 + jr]; \
  const float r = fast_sigmoid(xr + ((q0.x + q1.x) + (q2.x + q3.x))); \
  const float z = fast_sigmoid(xz + ((q0.y + q1.y) + (q2.y + q3.y))); \
  const float n = fast_tanh(xn + r * (((q0.z + q1.z) + (q2.z + q3.z)) + bh)); \
  const float hn = n + z * (hprev - n);      /* (1-z)*n + z*h */ \
  hprev = hn; \
  if (lane16) *hp = hn;                      /* wave w stores its 16 j's */ \
  hp += 64; \
  REP16(RL) \
}

__global__ __launch_bounds__(256, 1) void scan_kernel(
    const float* __restrict__ gates,
    const float* __restrict__ Whr, const float* __restrict__ Whz,
    const float* __restrict__ Whn, const float* __restrict__ bhn,
    float* __restrict__ hs)
{
  __shared__ float sW[3 * 4096];
  __shared__ float4_t partf4[512];   // [2 buf][4 src-wave][64 j] of {r,z,n,pad}
  const int tid = threadIdx.x;
  const int j = tid & 63;            // lane
  const int wid = tid >> 6;          // wave 0..3
  const int kbase = wid * 16;        // this wave's k-chunk
  const int wslot = wid * 64;        // float4 index of this wave's partial row
  const int l15 = j & 15;
  const int jr = kbase + l15;        // tail output owned by this lane (4x redundant)
  const bool lane16 = (j < 16);

  // stage weights coalesced (256 threads)
  for (int i = tid; i < 4096; i += 256) {
    sW[i] = Whr[i];
    sW[4096 + i] = Whz[i];
    sW[8192 + i] = Whn[i];
  }
  __syncthreads();

  REP16(DECLW)
  REP16(INITW)
  REP16(PINW)
  float bh = bhn[jr];
  asm volatile("" : "+v"(bh));

  REP16(DECLH)                       // uniform h chunk (SGPRs via readlane), h0 = 0
  float hprev = 0.0f;

  // gate prefetch ring, distance 4 (gates L2/L3-resident after prep)
  REP4(DECLP)
  {
    const float* g0 = gates + jr;
    REP4(PROLOAD)
  }
  const float* gpf = gates + jr + (size_t)4 * 192;  // overruns 3KB into hs region: values discarded, safe
  float* hp = hs + jr;

  for (int tb = 0; tb < T_LEN / 4; tb++) {
    STEP(0)
    STEP(1)
    STEP(2)
    STEP(3)
  }
  // Double-buffered partials (d&1) + one LDS barrier/step: a wave's reads of
  // buf b complete before it can reach the next barrier (compiler waitcnts
  // reads before the tail that feeds the next write), and buf b is only
  // rewritten after that barrier — no race.
}

// ---------------------------------------------------------------------------
// Kernel C (parallel over T): out[t][k] = hs[t] . Wend[:,perm[k]] + bend[perm[k]]
// perm = [1,0,3,2]
// ---------------------------------------------------------------------------
__global__ __launch_bounds__(256) void out_kernel(
    const float* __restrict__ hs, const float* __restrict__ Wend,
    const float* __restrict__ bend, float* __restrict__ out)
{
  __shared__ float4_t sWe[64];
  __shared__ float sbe[4];
  if (threadIdx.x < 64) sWe[threadIdx.x] = ((const float4_t*)Wend)[threadIdx.x];
  if (threadIdx.x < 4) sbe[threadIdx.x] = bend[threadIdx.x];
  __syncthreads();

  const int t = blockIdx.x * 256 + threadIdx.x;
  const float4_t* hp = (const float4_t*)(hs + (size_t)t * 64);
  float a0 = sbe[1], a1 = sbe[0], a2 = sbe[3], a3 = sbe[2];
#pragma unroll
  for (int c = 0; c < 16; c++) {
    const float4_t hv = hp[c];
#pragma unroll
    for (int q = 0; q < 4; q++) {
      const float hvq = hv[q];
      const float4_t w = sWe[c * 4 + q];   // Wend row, broadcast
      a0 += hvq * w.y;
      a1 += hvq * w.x;
      a2 += hvq * w.w;
      a3 += hvq * w.z;
    }
  }
  float4_t res = {a0, a1, a2, a3};
  ((float4_t*)out)[t] = res;
}

// ---------------------------------------------------------------------------
extern "C" void kernel_launch(void* const* d_in, const int* in_sizes, int n_in,
                              void* d_out, int out_size, void* d_ws, size_t ws_size,
                              hipStream_t stream) {
  (void)in_sizes; (void)n_in; (void)out_size; (void)ws_size;
  const float* obs  = (const float*)d_in[0];
  const float* W1   = (const float*)d_in[1];
  const float* b1   = (const float*)d_in[2];
  const float* Wir  = (const float*)d_in[3];
  const float* bir  = (const float*)d_in[4];
  const float* Wiz  = (const float*)d_in[5];
  const float* biz  = (const float*)d_in[6];
  const float* Win  = (const float*)d_in[7];
  const float* bin  = (const float*)d_in[8];
  const float* Whr  = (const float*)d_in[9];
  const float* Whz  = (const float*)d_in[10];
  const float* Whn  = (const float*)d_in[11];
  const float* bhn  = (const float*)d_in[12];
  const float* Wend = (const float*)d_in[13];
  const float* bend = (const float*)d_in[14];
  float* out = (float*)d_out;

  float* gates = (float*)d_ws;                    // [T,3,64] fp32 = 100.7 MB
  float* hs = gates + (size_t)T_LEN * 192;        // [T,64]   fp32 =  33.6 MB

  prep_kernel<<<T_LEN / 256, 256, 0, stream>>>(obs, W1, b1, Wir, bir, Wiz, biz,
                                               Win, bin, gates);
  scan_kernel<<<1, 256, 0, stream>>>(gates, Whr, Whz, Whn, bhn, hs);
  out_kernel<<<T_LEN / 256, 256, 0, stream>>>(hs, Wend, bend, out);
}

// Round 6
// 46608.142 us; speedup vs baseline: 1.0112x; 1.0112x over previous
//
#include <hip/hip_runtime.h>
#include <cstddef>

#define T_LEN 131072

typedef float float4_t __attribute__((ext_vector_type(4)));

__device__ __forceinline__ float fast_sigmoid(float x) {
  float e = __builtin_amdgcn_exp2f(x * -1.44269504088896340736f);
  return __builtin_amdgcn_rcpf(1.0f + e);
}

__device__ __forceinline__ float fast_tanh(float x) {
  float e = __builtin_amdgcn_exp2f(x * 2.88539008177792681472f);
  return 1.0f - 2.0f * __builtin_amdgcn_rcpf(1.0f + e);
}

// ---------------------------------------------------------------------------
// Kernel A (parallel over T): hs_in = relu(x@W1+b1); gates[t] = hs_in @ {Wir,Wiz,Win} + b
// gates layout: [T][3][64] fp32
// ---------------------------------------------------------------------------
__global__ __launch_bounds__(256) void prep_kernel(
    const float* __restrict__ obs, const float* __restrict__ W1,
    const float* __restrict__ b1,
    const float* __restrict__ Wir, const float* __restrict__ bir,
    const float* __restrict__ Wiz, const float* __restrict__ biz,
    const float* __restrict__ Win, const float* __restrict__ bin,
    float* __restrict__ gates)
{
  __shared__ float sW1[36 * 64];
  __shared__ float sWg[3 * 4096];
  __shared__ float sb1[64];
  __shared__ float sbg[3 * 64];
  for (int i = threadIdx.x; i < 36 * 64; i += 256) sW1[i] = W1[i];
  for (int i = threadIdx.x; i < 4096; i += 256) {
    sWg[i] = Wir[i];
    sWg[4096 + i] = Wiz[i];
    sWg[8192 + i] = Win[i];
  }
  if (threadIdx.x < 64) {
    sb1[threadIdx.x] = b1[threadIdx.x];
    sbg[threadIdx.x] = bir[threadIdx.x];
    sbg[64 + threadIdx.x] = biz[threadIdx.x];
    sbg[128 + threadIdx.x] = bin[threadIdx.x];
  }
  __syncthreads();

  const int t = blockIdx.x * 256 + threadIdx.x;   // T divisible by 256

  float4_t x4[9];
  {
    const float4_t* op = (const float4_t*)(obs + (size_t)t * 36);
#pragma unroll
    for (int c = 0; c < 9; c++) x4[c] = op[c];
  }
  float4_t hacc[16];
  {
    const float4_t* bv = (const float4_t*)sb1;
#pragma unroll
    for (int k = 0; k < 16; k++) hacc[k] = bv[k];
  }
#pragma unroll
  for (int c = 0; c < 9; c++) {
#pragma unroll
    for (int q = 0; q < 4; q++) {
      const float xv = x4[c][q];
      const float4_t* wrow = (const float4_t*)(sW1 + (c * 4 + q) * 64);
#pragma unroll
      for (int k = 0; k < 16; k++) hacc[k] += xv * wrow[k];
    }
  }
#pragma unroll
  for (int k = 0; k < 16; k++) {
    hacc[k].x = fmaxf(hacc[k].x, 0.0f);
    hacc[k].y = fmaxf(hacc[k].y, 0.0f);
    hacc[k].z = fmaxf(hacc[k].z, 0.0f);
    hacc[k].w = fmaxf(hacc[k].w, 0.0f);
  }

  float* gout = gates + (size_t)t * 192;
  for (int g = 0; g < 3; g++) {   // rolled: caps register pressure
    const float* wg = sWg + g * 4096;
    float4_t acc[16];
    {
      const float4_t* bv = (const float4_t*)(sbg + g * 64);
#pragma unroll
      for (int k = 0; k < 16; k++) acc[k] = bv[k];
    }
#pragma unroll
    for (int ii = 0; ii < 16; ii++) {
      const float4_t hv4 = hacc[ii];
#pragma unroll
      for (int q = 0; q < 4; q++) {
        const float hv = hv4[q];
        const float4_t* wrow = (const float4_t*)(wg + (ii * 4 + q) * 64);
#pragma unroll
        for (int k = 0; k < 16; k++) acc[k] += hv * wrow[k];
      }
    }
    float4_t* outp = (float4_t*)(gout + g * 64);
#pragma unroll
    for (int k = 0; k < 16; k++) outp[k] = acc[k];
  }
}

// ---------------------------------------------------------------------------
// Kernel B (sequential): 4 waves, K-split GRU scan. FP32.
// R5 post-mortem: R2..R5 all pinned at ~850 cyc/step despite 4x different
// inner loops — the shared element was a per-step asm "memory" clobber.
// A memory-clobber asm may READ memory, so the waitcnt pass must drain all
// outstanding STORES (vmcnt in-order => also all older gate loads) before
// it: every step blocked on a global-store ack (~600-900 cyc). Fix: the
// barrier below is a clobber-FREE volatile asm (lgkmcnt-only drain +
// s_barrier, CK block_sync_lds style). No IR memory effects => no vmcnt
// waits; MI-level side effects still chain-order it with all DS ops.
// Cross-step LDS value-forwarding is blocked by runtime (may-alias) indices.
// ---------------------------------------------------------------------------
#define REP16(X) X(0) X(1) X(2) X(3) X(4) X(5) X(6) X(7) \
                 X(8) X(9) X(10) X(11) X(12) X(13) X(14) X(15)
#define REP8(X) X(0) X(1) X(2) X(3) X(4) X(5) X(6) X(7)

#define DECLW(c) float wr##c, wz##c, wn##c;
#define INITW(c) \
  wr##c = sW[(kbase + (c)) * 64 + j]; \
  wz##c = sW[4096 + (kbase + (c)) * 64 + j]; \
  wn##c = sW[8192 + (kbase + (c)) * 64 + j];
#define PINW(c) asm volatile("" : "+v"(wr##c), "+v"(wz##c), "+v"(wn##c));

#define DECLH(c) float hh##c = 0.0f;
#define RL(c) hh##c = __builtin_bit_cast(float, \
    __builtin_amdgcn_readlane(__builtin_bit_cast(int, hn), (c)));

// two k-elements of all three gate partials: 6 scalar v_fma_f32 (SGPR h src)
#define FMA2(ce, co) \
  sR0 = __builtin_fmaf(wr##ce, hh##ce, sR0); sR1 = __builtin_fmaf(wr##co, hh##co, sR1); \
  sZ0 = __builtin_fmaf(wz##ce, hh##ce, sZ0); sZ1 = __builtin_fmaf(wz##co, hh##co, sZ1); \
  sN0 = __builtin_fmaf(wn##ce, hh##ce, sN0); sN1 = __builtin_fmaf(wn##co, hh##co, sN1);

#define DECLP(d) float pr##d, pz##d, pn##d;
#define PROLOAD(d) \
  pr##d = g0[(d) * 192]; \
  pz##d = g0[(d) * 192 + 64]; \
  pn##d = g0[(d) * 192 + 128];

// LDS-only barrier, NO memory clobber: drains lgkm only; global loads/stores
// stay in flight (a "memory" clobber here forces a vmcnt store-drain — the
// R2..R5 850-cyc/step bug).
#define LDS_BARRIER() asm volatile("s_waitcnt lgkmcnt(0)\n\ts_barrier")

#define STEP(d) { \
  const float xr = pr##d, xz = pz##d, xn = pn##d; \
  pr##d = gpf[0]; pz##d = gpf[64]; pn##d = gpf[128]; gpf += 192; \
  float sR0 = 0.f, sR1 = 0.f, sZ0 = 0.f, sZ1 = 0.f, sN0 = 0.f, sN1 = 0.f; \
  FMA2(0,1) FMA2(2,3) FMA2(4,5) FMA2(6,7) \
  FMA2(8,9) FMA2(10,11) FMA2(12,13) FMA2(14,15) \
  partf4[((d)&1)*256 + wslot + j] = float4_t{sR0 + sR1, sZ0 + sZ1, sN0 + sN1, 0.0f}; \
  LDS_BARRIER(); \
  const float4_t q0 = partf4[((d)&1)*256 +       jr]; \
  const float4_t q1 = partf4[((d)&1)*256 +  64 + jr]; \
  const float4_t q2 = partf4[((d)&1)*256 + 128 + jr]; \
  const float4_t q3 = partf4[((d)&1)*256 + 192 + jr]; \
  const float r = fast_sigmoid(xr + ((q0.x + q1.x) + (q2.x + q3.x))); \
  const float z = fast_sigmoid(xz + ((q0.y + q1.y) + (q2.y + q3.y))); \
  const float n = fast_tanh(xn + r * (((q0.z + q1.z) + (q2.z + q3.z)) + bh)); \
  const float hn = n + z * (hprev - n);      /* (1-z)*n + z*h */ \
  hprev = hn; \
  REP16(RL)                                  /* broadcast own k-chunk, SGPRs */ \
  if (lane16) *hp = hn;                      /* wave w stores its 16 j's */ \
  hp += 64; \
}

__global__ __launch_bounds__(256, 1) void scan_kernel(
    const float* __restrict__ gates,
    const float* __restrict__ Whr, const float* __restrict__ Whz,
    const float* __restrict__ Whn, const float* __restrict__ bhn,
    float* __restrict__ hs)
{
  __shared__ float sW[3 * 4096];
  __shared__ float4_t partf4[512];   // [2 buf][4 src-wave][64 j] of {r,z,n,pad}
  const int tid = threadIdx.x;
  const int j = tid & 63;            // lane
  const int wid = tid >> 6;          // wave 0..3
  const int kbase = wid * 16;        // this wave's k-chunk
  const int wslot = wid * 64;        // float4 index of this wave's partial row
  const int l15 = j & 15;
  const int jr = kbase + l15;        // tail output owned by this lane (4x redundant)
  const bool lane16 = (j < 16);

  // stage weights coalesced (256 threads)
  for (int i = tid; i < 4096; i += 256) {
    sW[i] = Whr[i];
    sW[4096 + i] = Whz[i];
    sW[8192 + i] = Whn[i];
  }
  __syncthreads();

  REP16(DECLW)
  REP16(INITW)
  REP16(PINW)
  float bh = bhn[jr];
  asm volatile("" : "+v"(bh));

  REP16(DECLH)                       // uniform h chunk (SGPRs via readlane), h0 = 0
  float hprev = 0.0f;

  // gate prefetch ring, distance 8 (gates L2/L3-resident after prep; cover
  // = 8 steps x ~460 cyc >> 900 cyc HBM latency)
  REP8(DECLP)
  {
    const float* g0 = gates + jr;
    REP8(PROLOAD)
  }
  const float* gpf = gates + jr + (size_t)8 * 192;  // overruns 6KB into hs region: values discarded, safe
  float* hp = hs + jr;

  for (int tb = 0; tb < T_LEN / 8; tb++) {
    STEP(0)
    STEP(1)
    STEP(2)
    STEP(3)
    STEP(4)
    STEP(5)
    STEP(6)
    STEP(7)
  }
  // Double-buffered partials (d&1) + one LDS barrier/step: a wave's reads of
  // buf b are lgkm-drained before it can issue the next step's write (data
  // dep through the tail), and buf b is only rewritten after the NEXT
  // barrier — no race.
}

// ---------------------------------------------------------------------------
// Kernel C (parallel over T): out[t][k] = hs[t] . Wend[:,perm[k]] + bend[perm[k]]
// perm = [1,0,3,2]
// ---------------------------------------------------------------------------
__global__ __launch_bounds__(256) void out_kernel(
    const float* __restrict__ hs, const float* __restrict__ Wend,
    const float* __restrict__ bend, float* __restrict__ out)
{
  __shared__ float4_t sWe[64];
  __shared__ float sbe[4];
  if (threadIdx.x < 64) sWe[threadIdx.x] = ((const float4_t*)Wend)[threadIdx.x];
  if (threadIdx.x < 4) sbe[threadIdx.x] = bend[threadIdx.x];
  __syncthreads();

  const int t = blockIdx.x * 256 + threadIdx.x;
  const float4_t* hp = (const float4_t*)(hs + (size_t)t * 64);
  float a0 = sbe[1], a1 = sbe[0], a2 = sbe[3], a3 = sbe[2];
#pragma unroll
  for (int c = 0; c < 16; c++) {
    const float4_t hv = hp[c];
#pragma unroll
    for (int q = 0; q < 4; q++) {
      const float hvq = hv[q];
      const float4_t w = sWe[c * 4 + q];   // Wend row, broadcast
      a0 += hvq * w.y;
      a1 += hvq * w.x;
      a2 += hvq * w.w;
      a3 += hvq * w.z;
    }
  }
  float4_t res = {a0, a1, a2, a3};
  ((float4_t*)out)[t] = res;
}

// ---------------------------------------------------------------------------
extern "C" void kernel_launch(void* const* d_in, const int* in_sizes, int n_in,
                              void* d_out, int out_size, void* d_ws, size_t ws_size,
                              hipStream_t stream) {
  (void)in_sizes; (void)n_in; (void)out_size; (void)ws_size;
  const float* obs  = (const float*)d_in[0];
  const float* W1   = (const float*)d_in[1];
  const float* b1   = (const float*)d_in[2];
  const float* Wir  = (const float*)d_in[3];
  const float* bir  = (const float*)d_in[4];
  const float* Wiz  = (const float*)d_in[5];
  const float* biz  = (const float*)d_in[6];
  const float* Win  = (const float*)d_in[7];
  const float* bin  = (const float*)d_in[8];
  const float* Whr  = (const float*)d_in[9];
  const float* Whz  = (const float*)d_in[10];
  const float* Whn  = (const float*)d_in[11];
  const float* bhn  = (const float*)d_in[12];
  const float* Wend = (const float*)d_in[13];
  const float* bend = (const float*)d_in[14];
  float* out = (float*)d_out;

  float* gates = (float*)d_ws;                    // [T,3,64] fp32 = 100.7 MB
  float* hs = gates + (size_t)T_LEN * 192;        // [T,64]   fp32 =  33.6 MB

  prep_kernel<<<T_LEN / 256, 256, 0, stream>>>(obs, W1, b1, Wir, bir, Wiz, biz,
                                               Win, bin, gates);
  scan_kernel<<<1, 256, 0, stream>>>(gates, Whr, Whz, Whn, bhn, hs);
  out_kernel<<<T_LEN / 256, 256, 0, stream>>>(hs, Wend, bend, out);
}

// Round 7
// 44998.972 us; speedup vs baseline: 1.0473x; 1.0358x over previous
//
#include <hip/hip_runtime.h>
#include <cstddef>

#define T_LEN 131072
#define CH 16                       // steps per chunk (gate staging / hs flush granularity)
#define NCH (T_LEN / CH)

typedef float float4_t __attribute__((ext_vector_type(4)));

__device__ __forceinline__ float fast_sigmoid(float x) {
  float e = __builtin_amdgcn_exp2f(x * -1.44269504088896340736f);
  return __builtin_amdgcn_rcpf(1.0f + e);
}

__device__ __forceinline__ float fast_tanh(float x) {
  float e = __builtin_amdgcn_exp2f(x * 2.88539008177792681472f);
  return 1.0f - 2.0f * __builtin_amdgcn_rcpf(1.0f + e);
}

// ---------------------------------------------------------------------------
// Kernel A (parallel over T): hs_in = relu(x@W1+b1); gates[t] = hs_in @ {Wir,Wiz,Win} + b
// gates layout: [T][3][64] fp32
// ---------------------------------------------------------------------------
__global__ __launch_bounds__(256) void prep_kernel(
    const float* __restrict__ obs, const float* __restrict__ W1,
    const float* __restrict__ b1,
    const float* __restrict__ Wir, const float* __restrict__ bir,
    const float* __restrict__ Wiz, const float* __restrict__ biz,
    const float* __restrict__ Win, const float* __restrict__ bin,
    float* __restrict__ gates)
{
  __shared__ float sW1[36 * 64];
  __shared__ float sWg[3 * 4096];
  __shared__ float sb1[64];
  __shared__ float sbg[3 * 64];
  for (int i = threadIdx.x; i < 36 * 64; i += 256) sW1[i] = W1[i];
  for (int i = threadIdx.x; i < 4096; i += 256) {
    sWg[i] = Wir[i];
    sWg[4096 + i] = Wiz[i];
    sWg[8192 + i] = Win[i];
  }
  if (threadIdx.x < 64) {
    sb1[threadIdx.x] = b1[threadIdx.x];
    sbg[threadIdx.x] = bir[threadIdx.x];
    sbg[64 + threadIdx.x] = biz[threadIdx.x];
    sbg[128 + threadIdx.x] = bin[threadIdx.x];
  }
  __syncthreads();

  const int t = blockIdx.x * 256 + threadIdx.x;   // T divisible by 256

  float4_t x4[9];
  {
    const float4_t* op = (const float4_t*)(obs + (size_t)t * 36);
#pragma unroll
    for (int c = 0; c < 9; c++) x4[c] = op[c];
  }
  float4_t hacc[16];
  {
    const float4_t* bv = (const float4_t*)sb1;
#pragma unroll
    for (int k = 0; k < 16; k++) hacc[k] = bv[k];
  }
#pragma unroll
  for (int c = 0; c < 9; c++) {
#pragma unroll
    for (int q = 0; q < 4; q++) {
      const float xv = x4[c][q];
      const float4_t* wrow = (const float4_t*)(sW1 + (c * 4 + q) * 64);
#pragma unroll
      for (int k = 0; k < 16; k++) hacc[k] += xv * wrow[k];
    }
  }
#pragma unroll
  for (int k = 0; k < 16; k++) {
    hacc[k].x = fmaxf(hacc[k].x, 0.0f);
    hacc[k].y = fmaxf(hacc[k].y, 0.0f);
    hacc[k].z = fmaxf(hacc[k].z, 0.0f);
    hacc[k].w = fmaxf(hacc[k].w, 0.0f);
  }

  float* gout = gates + (size_t)t * 192;
  for (int g = 0; g < 3; g++) {   // rolled: caps register pressure
    const float* wg = sWg + g * 4096;
    float4_t acc[16];
    {
      const float4_t* bv = (const float4_t*)(sbg + g * 64);
#pragma unroll
      for (int k = 0; k < 16; k++) acc[k] = bv[k];
    }
#pragma unroll
    for (int ii = 0; ii < 16; ii++) {
      const float4_t hv4 = hacc[ii];
#pragma unroll
      for (int q = 0; q < 4; q++) {
        const float hv = hv4[q];
        const float4_t* wrow = (const float4_t*)(wg + (ii * 4 + q) * 64);
#pragma unroll
        for (int k = 0; k < 16; k++) acc[k] += hv * wrow[k];
      }
    }
    float4_t* outp = (float4_t*)(gout + g * 64);
#pragma unroll
    for (int k = 0; k < 16; k++) outp[k] = acc[k];
  }
}

// ---------------------------------------------------------------------------
// Kernel B (sequential): 4 waves, K-split GRU scan, VMEM-FREE INNER LOOP.
// R6 post-mortem: R2..R6 (five different loops) all pinned at ~46 ms —
// the only invariants were the per-step global gate loads + h store. This
// version removes ALL per-step VMEM: gates are bulk-staged into LDS in
// 16-step chunks (loads issued at chunk top, ds_write at boundary 16 steps
// later => vmcnt waits hit 3µs-old loads = free); h outputs staged in a
// 4KB LDS ring, flushed once/16 steps as 256-lane dwordx4 stores (never
// waited on). Steady state: DS + VALU only.
// Within-wave ordering: every dangerous reorder pair is same-array
// may-alias (partf4 r/w, hstage r/w, gstage r/w) => alias analysis pins
// program order. Cross-wave: clobber-free lgkm-drain + s_barrier.
// ---------------------------------------------------------------------------
#define REP16(X) X(0) X(1) X(2) X(3) X(4) X(5) X(6) X(7) \
                 X(8) X(9) X(10) X(11) X(12) X(13) X(14) X(15)

#define DECLW(c) float wr##c, wz##c, wn##c;
#define INITW(c) \
  wr##c = sW[(kbase + (c)) * 64 + j]; \
  wz##c = sW[4096 + (kbase + (c)) * 64 + j]; \
  wn##c = sW[8192 + (kbase + (c)) * 64 + j];
#define PINW(c) asm volatile("" : "+v"(wr##c), "+v"(wz##c), "+v"(wn##c));

#define DECLH(c) float hh##c = 0.0f;
#define RL(c) hh##c = __builtin_bit_cast(float, \
    __builtin_amdgcn_readlane(__builtin_bit_cast(int, hn), (c)));

// two k-elements of all three gate partials: 6 scalar v_fma_f32 (SGPR h src)
#define FMA2(ce, co) \
  sR0 = __builtin_fmaf(wr##ce, hh##ce, sR0); sR1 = __builtin_fmaf(wr##co, hh##co, sR1); \
  sZ0 = __builtin_fmaf(wz##ce, hh##ce, sZ0); sZ1 = __builtin_fmaf(wz##co, hh##co, sZ1); \
  sN0 = __builtin_fmaf(wn##ce, hh##ce, sN0); sN1 = __builtin_fmaf(wn##co, hh##co, sN1);

// LDS-only barrier, NO memory clobber (no vmcnt side effects).
#define LDS_BARRIER() asm volatile("s_waitcnt lgkmcnt(0)\n\ts_barrier")

#define STEP(s) { \
  const float xr = gcur[(s)*192 + jr]; \
  const float xz = gcur[(s)*192 + 64 + jr]; \
  const float xn = gcur[(s)*192 + 128 + jr]; \
  float sR0 = 0.f, sR1 = 0.f, sZ0 = 0.f, sZ1 = 0.f, sN0 = 0.f, sN1 = 0.f; \
  FMA2(0,1) FMA2(2,3) FMA2(4,5) FMA2(6,7) \
  FMA2(8,9) FMA2(10,11) FMA2(12,13) FMA2(14,15) \
  partf4[((s)&1)*256 + wslot + j] = float4_t{sR0 + sR1, sZ0 + sZ1, sN0 + sN1, 0.0f}; \
  LDS_BARRIER(); \
  const float4_t q0 = partf4[((s)&1)*256 +       jr]; \
  const float4_t q1 = partf4[((s)&1)*256 +  64 + jr]; \
  const float4_t q2 = partf4[((s)&1)*256 + 128 + jr]; \
  const float4_t q3 = partf4[((s)&1)*256 + 192 + jr]; \
  const float r = fast_sigmoid(xr + ((q0.x + q1.x) + (q2.x + q3.x))); \
  const float z = fast_sigmoid(xz + ((q0.y + q1.y) + (q2.y + q3.y))); \
  const float n = fast_tanh(xn + r * (((q0.z + q1.z) + (q2.z + q3.z)) + bh)); \
  const float hn = n + z * (hprev - n);      /* (1-z)*n + z*h */ \
  hprev = hn; \
  REP16(RL)                                  /* broadcast own k-chunk, SGPRs */ \
  if (lane16) hstage[(s)*64 + jr] = hn;      /* LDS stage, flushed per chunk */ \
}

__global__ __launch_bounds__(256, 1) void scan_kernel(
    const float* __restrict__ gates,
    const float* __restrict__ Whr, const float* __restrict__ Whz,
    const float* __restrict__ Whn, const float* __restrict__ bhn,
    float* __restrict__ hs)
{
  __shared__ float sW[3 * 4096];          // 48 KB weights
  __shared__ float4_t partf4[512];        // 8 KB: [2 buf][4 src-wave][64 j] partials
  __shared__ float gstage[2 * CH * 192];  // 24 KB: double-buffered gate chunks
  __shared__ float hstage[CH * 64];       // 4 KB: h output staging ring
  const int tid = threadIdx.x;
  const int j = tid & 63;            // lane
  const int wid = tid >> 6;          // wave 0..3
  const int kbase = wid * 16;        // this wave's k-chunk
  const int wslot = wid * 64;        // float4 index of this wave's partial row
  const int l15 = j & 15;
  const int jr = kbase + l15;        // tail output owned by this lane (4x redundant)
  const bool lane16 = (j < 16);

  // stage weights coalesced (256 threads)
  for (int i = tid; i < 4096; i += 256) {
    sW[i] = Whr[i];
    sW[4096 + i] = Whz[i];
    sW[8192 + i] = Whn[i];
  }
  __syncthreads();

  REP16(DECLW)
  REP16(INITW)
  REP16(PINW)
  float bh = bhn[jr];
  asm volatile("" : "+v"(bh));

  REP16(DECLH)                       // uniform h chunk (SGPRs via readlane), h0 = 0
  float hprev = 0.0f;

  // prologue: stage gate chunk 0 into buffer 0
  {
    const float4_t* gsrc = (const float4_t*)gates;
    const float4_t a = gsrc[tid], b = gsrc[256 + tid], c = gsrc[512 + tid];
    float4_t* gdst = (float4_t*)gstage;
    gdst[tid] = a; gdst[256 + tid] = b; gdst[512 + tid] = c;
  }
  LDS_BARRIER();

  for (int c = 0; c < NCH; c++) {
    // issue next chunk's gate loads now; consumed (ds_write) 16 steps later,
    // so the compiler's vmcnt wait lands on long-retired loads.
    // c+1 == NCH overruns 12KB into the hs region: values discarded, safe.
    const float4_t* gsrc = (const float4_t*)(gates + (size_t)(c + 1) * (CH * 192));
    const float4_t ga = gsrc[tid], gb = gsrc[256 + tid], gc = gsrc[512 + tid];

    const float* gcur = gstage + (c & 1) * (CH * 192);
    STEP(0)  STEP(1)  STEP(2)  STEP(3)
    STEP(4)  STEP(5)  STEP(6)  STEP(7)
    STEP(8)  STEP(9)  STEP(10) STEP(11)
    STEP(12) STEP(13) STEP(14) STEP(15)

    LDS_BARRIER();   // drain step-15 hstage/partf4 writes across waves
    {
      // stage next gate chunk (vmcnt wait here is ~free: loads 16 steps old)
      float4_t* gdst = (float4_t*)(gstage + ((c + 1) & 1) * (CH * 192));
      gdst[tid] = ga; gdst[256 + tid] = gb; gdst[512 + tid] = gc;
      // flush hs chunk: 4 KB, coalesced dwordx4, stores never waited on
      const float4_t hv = ((const float4_t*)hstage)[tid];
      ((float4_t*)(hs + (size_t)c * (CH * 64)))[tid] = hv;
    }
    LDS_BARRIER();   // gstage visible to all; hstage reads drained before reuse
  }
}

// ---------------------------------------------------------------------------
// Kernel C (parallel over T): out[t][k] = hs[t] . Wend[:,perm[k]] + bend[perm[k]]
// perm = [1,0,3,2]
// ---------------------------------------------------------------------------
__global__ __launch_bounds__(256) void out_kernel(
    const float* __restrict__ hs, const float* __restrict__ Wend,
    const float* __restrict__ bend, float* __restrict__ out)
{
  __shared__ float4_t sWe[64];
  __shared__ float sbe[4];
  if (threadIdx.x < 64) sWe[threadIdx.x] = ((const float4_t*)Wend)[threadIdx.x];
  if (threadIdx.x < 4) sbe[threadIdx.x] = bend[threadIdx.x];
  __syncthreads();

  const int t = blockIdx.x * 256 + threadIdx.x;
  const float4_t* hp = (const float4_t*)(hs + (size_t)t * 64);
  float a0 = sbe[1], a1 = sbe[0], a2 = sbe[3], a3 = sbe[2];
#pragma unroll
  for (int c = 0; c < 16; c++) {
    const float4_t hv = hp[c];
#pragma unroll
    for (int q = 0; q < 4; q++) {
      const float hvq = hv[q];
      const float4_t w = sWe[c * 4 + q];   // Wend row, broadcast
      a0 += hvq * w.y;
      a1 += hvq * w.x;
      a2 += hvq * w.w;
      a3 += hvq * w.z;
    }
  }
  float4_t res = {a0, a1, a2, a3};
  ((float4_t*)out)[t] = res;
}

// ---------------------------------------------------------------------------
extern "C" void kernel_launch(void* const* d_in, const int* in_sizes, int n_in,
                              void* d_out, int out_size, void* d_ws, size_t ws_size,
                              hipStream_t stream) {
  (void)in_sizes; (void)n_in; (void)out_size; (void)ws_size;
  const float* obs  = (const float*)d_in[0];
  const float* W1   = (const float*)d_in[1];
  const float* b1   = (const float*)d_in[2];
  const float* Wir  = (const float*)d_in[3];
  const float* bir  = (const float*)d_in[4];
  const float* Wiz  = (const float*)d_in[5];
  const float* biz  = (const float*)d_in[6];
  const float* Win  = (const float*)d_in[7];
  const float* bin  = (const float*)d_in[8];
  const float* Whr  = (const float*)d_in[9];
  const float* Whz  = (const float*)d_in[10];
  const float* Whn  = (const float*)d_in[11];
  const float* bhn  = (const float*)d_in[12];
  const float* Wend = (const float*)d_in[13];
  const float* bend = (const float*)d_in[14];
  float* out = (float*)d_out;

  float* gates = (float*)d_ws;                    // [T,3,64] fp32 = 100.7 MB
  float* hs = gates + (size_t)T_LEN * 192;        // [T,64]   fp32 =  33.6 MB

  prep_kernel<<<T_LEN / 256, 256, 0, stream>>>(obs, W1, b1, Wir, bir, Wiz, biz,
                                               Win, bin, gates);
  scan_kernel<<<1, 256, 0, stream>>>(gates, Whr, Whz, Whn, bhn, hs);
  out_kernel<<<T_LEN / 256, 256, 0, stream>>>(hs, Wend, bend, out);
}